// Round 15
// baseline (8822.988 us; speedup 1.0000x reference)
//
#include <hip/hip_runtime.h>

// Persistent LSTM: B=64, T=512, F=512, H=1024. fp32 in/out, bf16 MFMA compute.
// gates[b,n]_t = sum_f x[b,t,f]U[f,n] + sum_k h[b,k]W[k,n] + bias[n]
// r14 base (256 blk x 512 thr, 8 waves = 4 gates x 2 K-halves, agent-scope
// h stores + flag release) with decongested consumer side:
//  - ONLY WAVE 0 polls the 64 flags (8x less LLC poll traffic)
//  - acquire-fence (L1/L2 inv) + PLAIN cached h loads: same-XCD same-bg
//    blocks share h lines through their L2 instead of 64x LLC service

#define Bz 64
#define Tz 512
#define Fz 512
#define Hz 1024
#define ROWP16 1544      // LDS row stride in u16: 1536 + 8 pad
#define ROWP64 386       // same in u64
#define NBLK 256
#define NTHR 512

typedef unsigned short u16;
typedef unsigned int u32;
typedef unsigned long long u64;
typedef __attribute__((ext_vector_type(8))) short bf16x8;
typedef __attribute__((ext_vector_type(4))) float f32x4;

__device__ __forceinline__ u16 f2bf(float f) {
    union { float f; unsigned u; } v; v.f = f;
    unsigned r = v.u + 0x7FFFu + ((v.u >> 16) & 1u);
    return (u16)(r >> 16);
}
__device__ __forceinline__ float fast_sigmoid(float x) {
    return 1.0f / (1.0f + __expf(-x));
}
__device__ __forceinline__ float fast_tanh(float x) {
    float e = __expf(2.0f * x);
    return 1.0f - 2.0f / (e + 1.0f);
}

// ---- prep kernels ----
__global__ __launch_bounds__(256) void conv_x_kernel(const float* __restrict__ x,
                                                     u16* __restrict__ xb) {
    size_t i = (size_t)blockIdx.x * 256 + threadIdx.x;
    float4 v = ((const float4*)x)[i];
    ushort4 o;
    o.x = f2bf(v.x); o.y = f2bf(v.y); o.z = f2bf(v.z); o.w = f2bf(v.w);
    ((ushort4*)xb)[i] = o;
}

__global__ __launch_bounds__(256) void transpose_tile_kernel(const float* __restrict__ src,
                                                             u16* __restrict__ dst,
                                                             int K, int N) {
    __shared__ u16 tile[32][33];
    const int ntk = K >> 5;
    const int tk = blockIdx.x % ntk;
    const int tn = blockIdx.x / ntk;
    const int c = threadIdx.x & 31;
    const int r0 = threadIdx.x >> 5;
#pragma unroll
    for (int rr = 0; rr < 32; rr += 8) {
        const int r = r0 + rr;
        tile[r][c] = f2bf(src[(size_t)(tk * 32 + r) * N + tn * 32 + c]);
    }
    __syncthreads();
#pragma unroll
    for (int rr = 0; rr < 32; rr += 8) {
        const int r = r0 + rr;
        dst[(size_t)(tn * 32 + r) * K + tk * 32 + c] = tile[c][r];
    }
}

__global__ __launch_bounds__(256) void init_state_kernel(u32* __restrict__ h0,
                                                         u32* __restrict__ flags) {
    int i = blockIdx.x * 256 + threadIdx.x;  // 32768 total
    h0[i] = 0u;
    if (i < 256) flags[i] = 0u;
}

// ---- persistent recurrent kernel ----
// Block (bg=blk>>6, jg=blk&63): batches [16bg,16bg+16), j in [16jg,16jg+16).
__global__ __launch_bounds__(NTHR, 1) void lstm_persist(
    const u16* __restrict__ xb,    // [B][T][F] bf16
    const u16* __restrict__ UT,    // [4096][512] bf16
    const u16* __restrict__ WT,    // [4096][1024] bf16
    const float* __restrict__ bias,// [4096]
    u64* __restrict__ h0,          // [B][256] bf16-quads (zeroed)
    u64* __restrict__ h1,
    float* __restrict__ out,       // hidden_seq | h_T | c_T
    u32* __restrict__ flags) {     // [4][64] producer flags

    __shared__ __align__(16) u16 albuf[16 * ROWP16];   // [x(512)|h(1024)|pad] x16
    __shared__ float gbuf[2][4 * 16 * 17];             // [khalf][gate][16m][17]

    const int tid = threadIdx.x;
    const int w = tid >> 6;       // 0..7
    const int g = w & 3;          // gate
    const int kh = w >> 2;        // K-half
    const int l = tid & 63;
    const int lr = l & 15;
    const int lk = l >> 4;
    const int bg = blockIdx.x >> 6;
    const int jg = blockIdx.x & 63;
    const int mbase = bg * 16;
    const int jbase = jg * 16;
    const int n = g * Hz + jbase + lr;   // global gate column

    // Weight slices: U kbs [kh*8, kh*8+8), W kbs [kh*16, kh*16+16)
    bf16x8 bwU[8], bwW[16];
    {
        const u16* Ub = UT + (size_t)n * Fz + kh * 256 + lk * 8;
        const u16* Wb = WT + (size_t)n * Hz + kh * 512 + lk * 8;
#pragma unroll
        for (int kb = 0; kb < 8; ++kb)  bwU[kb] = *(const bf16x8*)(Ub + kb * 32);
#pragma unroll
        for (int kb = 0; kb < 16; ++kb) bwW[kb] = *(const bf16x8*)(Wb + kb * 32);
    }

    // elementwise identity (threads 0..255 only)
    const int ml_e = (tid & 255) >> 4;
    const int jj_e = tid & 15;
    const int m_e = mbase + ml_e;
    const int j_e = jbase + jj_e;
    float creg = 0.0f;
    float bv4[4];
#pragma unroll
    for (int gg = 0; gg < 4; ++gg) bv4[gg] = bias[gg * Hz + jbase + jj_e];

    const size_t OFF_HT = (size_t)Bz * Tz * Hz;
    const size_t OFF_CT = OFF_HT + (size_t)Bz * Hz;

    const u32* __restrict__ flg = flags + bg * 64;

    // prefetch x_0
    bf16x8 tx[2], txn[2];
#pragma unroll
    for (int it = 0; it < 2; ++it) {
        int idx = it * NTHR + tid;
        int ml = idx >> 6, ci = idx & 63;
        tx[it] = *(const bf16x8*)(xb + ((size_t)(mbase + ml) * Tz + 0) * Fz + ci * 8);
    }

#pragma unroll 1
    for (int t = 0; t < Tz; ++t) {
        const u64* __restrict__ hin  = (t & 1) ? h1 : h0;
        u64* __restrict__ hout       = (t & 1) ? h0 : h1;

        // ---- A: x_t -> LDS ----
#pragma unroll
        for (int it = 0; it < 2; ++it) {
            int idx = it * NTHR + tid;
            int ml = idx >> 6, ci = idx & 63;
            *(bf16x8*)(albuf + ml * ROWP16 + ci * 8) = tx[it];
        }
        __syncthreads();

        // ---- D1: this wave's U half (no h dependence) ----
        f32x4 a0 = {0.f,0.f,0.f,0.f}, a1 = a0, a2 = a0, a3 = a0;
        {
            const u16* abase = albuf + lr * ROWP16 + kh * 256 + lk * 8;
#pragma unroll
            for (int kb = 0; kb < 8; kb += 4) {
                a0 = __builtin_amdgcn_mfma_f32_16x16x32_bf16(*(const bf16x8*)(abase + (kb+0)*32), bwU[kb+0], a0, 0,0,0);
                a1 = __builtin_amdgcn_mfma_f32_16x16x32_bf16(*(const bf16x8*)(abase + (kb+1)*32), bwU[kb+1], a1, 0,0,0);
                a2 = __builtin_amdgcn_mfma_f32_16x16x32_bf16(*(const bf16x8*)(abase + (kb+2)*32), bwU[kb+2], a2, 0,0,0);
                a3 = __builtin_amdgcn_mfma_f32_16x16x32_bf16(*(const bf16x8*)(abase + (kb+3)*32), bwU[kb+3], a3, 0,0,0);
            }
        }

        if (t) {
            // ---- flag wait: ONLY WAVE 0 polls; others park at barrier ----
            if (w == 0) {
                const unsigned tgt = (unsigned)t;
                u32 v = __hip_atomic_load(flg + l, __ATOMIC_RELAXED,
                                          __HIP_MEMORY_SCOPE_AGENT);
                while (!__all((int)(v >= tgt)))
                    v = __hip_atomic_load(flg + l, __ATOMIC_RELAXED,
                                          __HIP_MEMORY_SCOPE_AGENT);
            }
            __syncthreads();
            // acquire: invalidate stale L1/L2 lines so plain loads see LLC
            __builtin_amdgcn_fence(__ATOMIC_ACQUIRE, "agent");
        }

        // ---- C: h tile = 4096 u64, PLAIN cached loads (L2-shared) ----
        {
            u64 hv[8];
            const u64* hsrc = hin + (size_t)mbase * 256;
#pragma unroll
            for (int r = 0; r < 8; ++r)
                hv[r] = hsrc[r * NTHR + tid];

            // x-prefetch issued AFTER h loads: staging waits vmcnt(2) only
            if (t + 1 < Tz) {
#pragma unroll
                for (int it = 0; it < 2; ++it) {
                    int idx = it * NTHR + tid;
                    int ml = idx >> 6, ci = idx & 63;
                    txn[it] = *(const bf16x8*)(xb + ((size_t)(mbase + ml) * Tz + (t + 1)) * Fz + ci * 8);
                }
            }

            u64* albuf64 = (u64*)albuf;
#pragma unroll
            for (int r = 0; r < 8; ++r) {
                int idx = r * NTHR + tid;
                int ml = idx >> 8, ci = idx & 255;
                albuf64[ml * ROWP64 + 128 + ci] = hv[r];  // 128 u64 = 512 u16
            }
        }
        __syncthreads();

        // ---- D2: this wave's W half ----
        {
            const u16* abase = albuf + lr * ROWP16 + 512 + kh * 512 + lk * 8;
#pragma unroll
            for (int kb = 0; kb < 16; kb += 4) {
                a0 = __builtin_amdgcn_mfma_f32_16x16x32_bf16(*(const bf16x8*)(abase + (kb+0)*32), bwW[kb+0], a0, 0,0,0);
                a1 = __builtin_amdgcn_mfma_f32_16x16x32_bf16(*(const bf16x8*)(abase + (kb+1)*32), bwW[kb+1], a1, 0,0,0);
                a2 = __builtin_amdgcn_mfma_f32_16x16x32_bf16(*(const bf16x8*)(abase + (kb+2)*32), bwW[kb+2], a2, 0,0,0);
                a3 = __builtin_amdgcn_mfma_f32_16x16x32_bf16(*(const bf16x8*)(abase + (kb+3)*32), bwW[kb+3], a3, 0,0,0);
            }
        }
        f32x4 acc = (a0 + a1) + (a2 + a3);

        // ---- partial gate exchange: D row=(lk*4+i)=batch, col=lr ----
#pragma unroll
        for (int i = 0; i < 4; ++i)
            gbuf[kh][g * 272 + (lk * 4 + i) * 17 + lr] = acc[i];
        __syncthreads();

        // ---- elementwise on threads 0..255; packed agent-scope h store ----
        float hn = 0.0f, cn = 0.0f;
        if (tid < 256) {
            const int q = ml_e * 17 + jj_e;
            float fg = fast_sigmoid(gbuf[0][q]        + gbuf[1][q]        + bv4[0]);
            float ig = fast_sigmoid(gbuf[0][272 + q]  + gbuf[1][272 + q]  + bv4[1]);
            float og = fast_sigmoid(gbuf[0][544 + q]  + gbuf[1][544 + q]  + bv4[2]);
            float ct = fast_sigmoid(gbuf[0][816 + q]  + gbuf[1][816 + q]  + bv4[3]);
            cn = fg * creg + ig * ct;
            creg = cn;
            hn = og * fast_tanh(cn);
            float hn1 = __shfl_xor(hn, 1);
            u32 p01 = ((u32)f2bf(hn1) << 16) | (u32)f2bf(hn);   // valid on even jj
            u32 p23 = __shfl_xor(p01, 2);                       // pair (jj+2,jj+3)
            if (!(jj_e & 3)) {
                u64 pk = ((u64)p23 << 32) | (u64)p01;
                __hip_atomic_store(hout + (size_t)m_e * 256 + (j_e >> 2), pk,
                                   __ATOMIC_RELAXED, __HIP_MEMORY_SCOPE_AGENT);
            }
        }

        // ---- release: drain all waves' stores, then set own flag ----
        if (t != Tz - 1) {
            __syncthreads();  // per-wave vmcnt(0): h stores visible at LLC
            if (tid == 0)
                __hip_atomic_store((u32*)flg + jg, (u32)(t + 1),
                                   __ATOMIC_RELAXED, __HIP_MEMORY_SCOPE_AGENT);
        }

        // ---- off-critical-path: out store; rotate prefetch regs ----
        if (tid < 256) {
            out[((size_t)m_e * Tz + t) * Hz + j_e] = hn;
            if (t == Tz - 1) {
                out[OFF_HT + (size_t)m_e * Hz + j_e] = hn;
                out[OFF_CT + (size_t)m_e * Hz + j_e] = cn;
            }
        }
        tx[0] = txn[0];
        tx[1] = txn[1];
    }
}

extern "C" void kernel_launch(void* const* d_in, const int* in_sizes, int n_in,
                              void* d_out, int out_size, void* d_ws, size_t ws_size,
                              hipStream_t stream) {
    const float* x    = (const float*)d_in[0];  // [64][512][512]
    const float* U    = (const float*)d_in[1];  // [512][4096]
    const float* W    = (const float*)d_in[2];  // [1024][4096]
    const float* bias = (const float*)d_in[3];  // [4096]
    float* out = (float*)d_out;
    char* ws = (char*)d_ws;

    u16* xb    = (u16*)(ws + 0);          // 33,554,432 B
    u16* UT    = (u16*)(ws + 33554432);   //  4,194,304 B
    u16* WT    = (u16*)(ws + 37748736);   //  8,388,608 B
    u64* h0    = (u64*)(ws + 46137344);   //    131,072 B
    u64* h1    = (u64*)(ws + 46268416);   //    131,072 B
    u32* flags = (u32*)(ws + 46399488);   //      1,024 B

    conv_x_kernel<<<16384, 256, 0, stream>>>(x, xb);
    transpose_tile_kernel<<<2048, 256, 0, stream>>>(U, UT, 512, 4096);
    transpose_tile_kernel<<<4096, 256, 0, stream>>>(W, WT, 1024, 4096);
    init_state_kernel<<<128, 256, 0, stream>>>((u32*)h0, flags);

    lstm_persist<<<NBLK, NTHR, 0, stream>>>(xb, UT, WT, bias, h0, h1, out, flags);
}

// Round 16
// 1459.332 us; speedup vs baseline: 6.0459x; 6.0459x over previous
//
#include <hip/hip_runtime.h>

// Persistent LSTM: B=64, T=512, F=512, H=1024. fp32 in/out, bf16 MFMA compute.
// gates[b,n]_t = sum_f x[b,t,f]U[f,n] + sum_k h[b,k]W[k,n] + bias[n]
// r14 base (256 blk x 512 thr, 8 waves = 4 gates x 2 K-halves, flags at LLC,
// agent-scope u64 h exchange, early x-prefetch) + ONE change:
//  - hidden_seq HBM store issued BEFORE the release drain, so its write-ack
//    completes in parallel with the h-store's LLC ack inside the release
//    __syncthreads, instead of stalling the next step's first barrier.

#define Bz 64
#define Tz 512
#define Fz 512
#define Hz 1024
#define ROWP16 1544      // LDS row stride in u16: 1536 + 8 pad
#define ROWP64 386       // same in u64
#define NBLK 256
#define NTHR 512

typedef unsigned short u16;
typedef unsigned int u32;
typedef unsigned long long u64;
typedef __attribute__((ext_vector_type(8))) short bf16x8;
typedef __attribute__((ext_vector_type(4))) float f32x4;

__device__ __forceinline__ u16 f2bf(float f) {
    union { float f; unsigned u; } v; v.f = f;
    unsigned r = v.u + 0x7FFFu + ((v.u >> 16) & 1u);
    return (u16)(r >> 16);
}
__device__ __forceinline__ float fast_sigmoid(float x) {
    return 1.0f / (1.0f + __expf(-x));
}
__device__ __forceinline__ float fast_tanh(float x) {
    float e = __expf(2.0f * x);
    return 1.0f - 2.0f / (e + 1.0f);
}

// ---- prep kernels ----
__global__ __launch_bounds__(256) void conv_x_kernel(const float* __restrict__ x,
                                                     u16* __restrict__ xb) {
    size_t i = (size_t)blockIdx.x * 256 + threadIdx.x;
    float4 v = ((const float4*)x)[i];
    ushort4 o;
    o.x = f2bf(v.x); o.y = f2bf(v.y); o.z = f2bf(v.z); o.w = f2bf(v.w);
    ((ushort4*)xb)[i] = o;
}

__global__ __launch_bounds__(256) void transpose_tile_kernel(const float* __restrict__ src,
                                                             u16* __restrict__ dst,
                                                             int K, int N) {
    __shared__ u16 tile[32][33];
    const int ntk = K >> 5;
    const int tk = blockIdx.x % ntk;
    const int tn = blockIdx.x / ntk;
    const int c = threadIdx.x & 31;
    const int r0 = threadIdx.x >> 5;
#pragma unroll
    for (int rr = 0; rr < 32; rr += 8) {
        const int r = r0 + rr;
        tile[r][c] = f2bf(src[(size_t)(tk * 32 + r) * N + tn * 32 + c]);
    }
    __syncthreads();
#pragma unroll
    for (int rr = 0; rr < 32; rr += 8) {
        const int r = r0 + rr;
        dst[(size_t)(tn * 32 + r) * K + tk * 32 + c] = tile[c][r];
    }
}

__global__ __launch_bounds__(256) void init_state_kernel(u32* __restrict__ h0,
                                                         u32* __restrict__ flags) {
    int i = blockIdx.x * 256 + threadIdx.x;  // 32768 total
    h0[i] = 0u;
    if (i < 256) flags[i] = 0u;
}

// ---- persistent recurrent kernel ----
// Block (bg=blk>>6, jg=blk&63): batches [16bg,16bg+16), j in [16jg,16jg+16).
__global__ __launch_bounds__(NTHR, 1) void lstm_persist(
    const u16* __restrict__ xb,    // [B][T][F] bf16
    const u16* __restrict__ UT,    // [4096][512] bf16
    const u16* __restrict__ WT,    // [4096][1024] bf16
    const float* __restrict__ bias,// [4096]
    u64* __restrict__ h0,          // [B][256] bf16-quads (zeroed)
    u64* __restrict__ h1,
    float* __restrict__ out,       // hidden_seq | h_T | c_T
    u32* __restrict__ flags) {     // [4][64] producer flags

    __shared__ __align__(16) u16 albuf[16 * ROWP16];   // [x(512)|h(1024)|pad] x16
    __shared__ float gbuf[2][4 * 16 * 17];             // [khalf][gate][16m][17]

    const int tid = threadIdx.x;
    const int w = tid >> 6;       // 0..7
    const int g = w & 3;          // gate
    const int kh = w >> 2;        // K-half
    const int l = tid & 63;
    const int lr = l & 15;
    const int lk = l >> 4;
    const int bg = blockIdx.x >> 6;
    const int jg = blockIdx.x & 63;
    const int mbase = bg * 16;
    const int jbase = jg * 16;
    const int n = g * Hz + jbase + lr;   // global gate column

    // Weight slices: U kbs [kh*8, kh*8+8), W kbs [kh*16, kh*16+16)
    bf16x8 bwU[8], bwW[16];
    {
        const u16* Ub = UT + (size_t)n * Fz + kh * 256 + lk * 8;
        const u16* Wb = WT + (size_t)n * Hz + kh * 512 + lk * 8;
#pragma unroll
        for (int kb = 0; kb < 8; ++kb)  bwU[kb] = *(const bf16x8*)(Ub + kb * 32);
#pragma unroll
        for (int kb = 0; kb < 16; ++kb) bwW[kb] = *(const bf16x8*)(Wb + kb * 32);
    }

    // elementwise identity (threads 0..255 only)
    const int ml_e = (tid & 255) >> 4;
    const int jj_e = tid & 15;
    const int m_e = mbase + ml_e;
    const int j_e = jbase + jj_e;
    float creg = 0.0f;
    float bv4[4];
#pragma unroll
    for (int gg = 0; gg < 4; ++gg) bv4[gg] = bias[gg * Hz + jbase + jj_e];

    const size_t OFF_HT = (size_t)Bz * Tz * Hz;
    const size_t OFF_CT = OFF_HT + (size_t)Bz * Hz;

    const u32* __restrict__ flg = flags + bg * 64;
    u64* albuf64 = (u64*)albuf;

    // prefetch x_0
    bf16x8 tx[2], txn[2];
#pragma unroll
    for (int it = 0; it < 2; ++it) {
        int idx = it * NTHR + tid;
        int ml = idx >> 6, ci = idx & 63;
        tx[it] = *(const bf16x8*)(xb + ((size_t)(mbase + ml) * Tz + 0) * Fz + ci * 8);
    }

#pragma unroll 1
    for (int t = 0; t < Tz; ++t) {
        const u64* __restrict__ hin  = (t & 1) ? h1 : h0;
        u64* __restrict__ hout       = (t & 1) ? h0 : h1;

        // ---- A: x_t -> LDS ----
#pragma unroll
        for (int it = 0; it < 2; ++it) {
            int idx = it * NTHR + tid;
            int ml = idx >> 6, ci = idx & 63;
            *(bf16x8*)(albuf + ml * ROWP16 + ci * 8) = tx[it];
        }
        __syncthreads();

        // ---- issue x-prefetch(t+1): lands during this step ----
        if (t + 1 < Tz) {
#pragma unroll
            for (int it = 0; it < 2; ++it) {
                int idx = it * NTHR + tid;
                int ml = idx >> 6, ci = idx & 63;
                txn[it] = *(const bf16x8*)(xb + ((size_t)(mbase + ml) * Tz + (t + 1)) * Fz + ci * 8);
            }
        }

        // ---- issue first flag poll (resolves after D1) ----
        u32 pv = 0;
        if (t) pv = __hip_atomic_load(flg + l, __ATOMIC_RELAXED,
                                      __HIP_MEMORY_SCOPE_AGENT);

        // ---- D1: this wave's U half (no h dependence) ----
        f32x4 a0 = {0.f,0.f,0.f,0.f}, a1 = a0, a2 = a0, a3 = a0;
        {
            const u16* abase = albuf + lr * ROWP16 + kh * 256 + lk * 8;
#pragma unroll
            for (int kb = 0; kb < 8; kb += 4) {
                a0 = __builtin_amdgcn_mfma_f32_16x16x32_bf16(*(const bf16x8*)(abase + (kb+0)*32), bwU[kb+0], a0, 0,0,0);
                a1 = __builtin_amdgcn_mfma_f32_16x16x32_bf16(*(const bf16x8*)(abase + (kb+1)*32), bwU[kb+1], a1, 0,0,0);
                a2 = __builtin_amdgcn_mfma_f32_16x16x32_bf16(*(const bf16x8*)(abase + (kb+2)*32), bwU[kb+2], a2, 0,0,0);
                a3 = __builtin_amdgcn_mfma_f32_16x16x32_bf16(*(const bf16x8*)(abase + (kb+3)*32), bwU[kb+3], a3, 0,0,0);
            }
        }

        // ---- flag wait: first check uses pre-issued load ----
        if (t) {
            const unsigned tgt = (unsigned)t;
            u32 v = pv;
            while (!__all((int)(v >= tgt)))
                v = __hip_atomic_load(flg + l, __ATOMIC_RELAXED,
                                      __HIP_MEMORY_SCOPE_AGENT);
        }

        // ---- C: h tile = 4096 u64; 8 loads/thread, one round trip ----
        {
            u64 hv[8];
            const u64* hsrc = hin + (size_t)mbase * 256;
#pragma unroll
            for (int r = 0; r < 8; ++r)
                hv[r] = __hip_atomic_load(hsrc + r * NTHR + tid, __ATOMIC_RELAXED,
                                          __HIP_MEMORY_SCOPE_AGENT);
#pragma unroll
            for (int r = 0; r < 8; ++r) {
                int idx = r * NTHR + tid;
                int ml = idx >> 8, ci = idx & 255;
                albuf64[ml * ROWP64 + 128 + ci] = hv[r];  // 128 u64 = 512 u16
            }
        }
        __syncthreads();

        // ---- D2: this wave's W half ----
        {
            const u16* abase = albuf + lr * ROWP16 + 512 + kh * 512 + lk * 8;
#pragma unroll
            for (int kb = 0; kb < 16; kb += 4) {
                a0 = __builtin_amdgcn_mfma_f32_16x16x32_bf16(*(const bf16x8*)(abase + (kb+0)*32), bwW[kb+0], a0, 0,0,0);
                a1 = __builtin_amdgcn_mfma_f32_16x16x32_bf16(*(const bf16x8*)(abase + (kb+1)*32), bwW[kb+1], a1, 0,0,0);
                a2 = __builtin_amdgcn_mfma_f32_16x16x32_bf16(*(const bf16x8*)(abase + (kb+2)*32), bwW[kb+2], a2, 0,0,0);
                a3 = __builtin_amdgcn_mfma_f32_16x16x32_bf16(*(const bf16x8*)(abase + (kb+3)*32), bwW[kb+3], a3, 0,0,0);
            }
        }
        f32x4 acc = (a0 + a1) + (a2 + a3);

        // ---- partial gate exchange: D row=(lk*4+i)=batch, col=lr ----
#pragma unroll
        for (int i = 0; i < 4; ++i)
            gbuf[kh][g * 272 + (lk * 4 + i) * 17 + lr] = acc[i];
        __syncthreads();

        // ---- elementwise (threads 0..255); out store EARLY, then h store ----
        if (tid < 256) {
            const int q = ml_e * 17 + jj_e;
            float fg = fast_sigmoid(gbuf[0][q]        + gbuf[1][q]        + bv4[0]);
            float ig = fast_sigmoid(gbuf[0][272 + q]  + gbuf[1][272 + q]  + bv4[1]);
            float og = fast_sigmoid(gbuf[0][544 + q]  + gbuf[1][544 + q]  + bv4[2]);
            float ct = fast_sigmoid(gbuf[0][816 + q]  + gbuf[1][816 + q]  + bv4[3]);
            float cn = fg * creg + ig * ct;
            creg = cn;
            float hn = og * fast_tanh(cn);

            // out store FIRST: its HBM ack overlaps the release drain below
            out[((size_t)m_e * Tz + t) * Hz + j_e] = hn;
            if (t == Tz - 1) {
                out[OFF_HT + (size_t)m_e * Hz + j_e] = hn;
                out[OFF_CT + (size_t)m_e * Hz + j_e] = cn;
            }

            float hn1 = __shfl_xor(hn, 1);
            u32 p01 = ((u32)f2bf(hn1) << 16) | (u32)f2bf(hn);   // valid on even jj
            u32 p23 = __shfl_xor(p01, 2);                       // pair (jj+2,jj+3)
            if (!(jj_e & 3)) {
                u64 pk = ((u64)p23 << 32) | (u64)p01;
                __hip_atomic_store(hout + (size_t)m_e * 256 + (j_e >> 2), pk,
                                   __ATOMIC_RELAXED, __HIP_MEMORY_SCOPE_AGENT);
            }
        }

        // ---- release: drain (h ack || out ack in parallel), set flag ----
        if (t != Tz - 1) {
            __syncthreads();  // per-wave vmcnt(0): h + out stores both complete
            if (tid == 0)
                __hip_atomic_store((u32*)flg + jg, (u32)(t + 1),
                                   __ATOMIC_RELAXED, __HIP_MEMORY_SCOPE_AGENT);
        }

        // ---- rotate prefetch regs ----
        tx[0] = txn[0];
        tx[1] = txn[1];
    }
}

extern "C" void kernel_launch(void* const* d_in, const int* in_sizes, int n_in,
                              void* d_out, int out_size, void* d_ws, size_t ws_size,
                              hipStream_t stream) {
    const float* x    = (const float*)d_in[0];  // [64][512][512]
    const float* U    = (const float*)d_in[1];  // [512][4096]
    const float* W    = (const float*)d_in[2];  // [1024][4096]
    const float* bias = (const float*)d_in[3];  // [4096]
    float* out = (float*)d_out;
    char* ws = (char*)d_ws;

    u16* xb    = (u16*)(ws + 0);          // 33,554,432 B
    u16* UT    = (u16*)(ws + 33554432);   //  4,194,304 B
    u16* WT    = (u16*)(ws + 37748736);   //  8,388,608 B
    u64* h0    = (u64*)(ws + 46137344);   //    131,072 B
    u64* h1    = (u64*)(ws + 46268416);   //    131,072 B
    u32* flags = (u32*)(ws + 46399488);   //      1,024 B

    conv_x_kernel<<<16384, 256, 0, stream>>>(x, xb);
    transpose_tile_kernel<<<2048, 256, 0, stream>>>(U, UT, 512, 4096);
    transpose_tile_kernel<<<4096, 256, 0, stream>>>(W, WT, 1024, 4096);
    init_state_kernel<<<128, 256, 0, stream>>>((u32*)h0, flags);

    lstm_persist<<<NBLK, NTHR, 0, stream>>>(xb, UT, WT, bias, h0, h1, out, flags);
}